// Round 1
// baseline (522.625 us; speedup 1.0000x reference)
//
#include <hip/hip_runtime.h>
#include <math.h>

#define NS 2097152
#define FEAT 16
#define HID 64
#define IN_DIM 35

__global__ __launch_bounds__(256) void radiance_fp32_kernel(
    const float* __restrict__ features,
    const float* __restrict__ dirs,
    const float* __restrict__ normals,
    const float* __restrict__ W1,   // [35][64]
    const float* __restrict__ W2,   // [64][64]
    const float* __restrict__ W3,   // [64][3]
    float* __restrict__ out)        // [N][3]
{
    const int i = blockIdx.x * blockDim.x + threadIdx.x;

    // ---- load inputs ----
    float inp[IN_DIM];
    {
        const float4* fp = reinterpret_cast<const float4*>(features + (size_t)i * FEAT);
        float4 f0 = fp[0], f1 = fp[1], f2 = fp[2], f3 = fp[3];
        inp[0] = f0.x; inp[1] = f0.y; inp[2]  = f0.z; inp[3]  = f0.w;
        inp[4] = f1.x; inp[5] = f1.y; inp[6]  = f1.z; inp[7]  = f1.w;
        inp[8] = f2.x; inp[9] = f2.y; inp[10] = f2.z; inp[11] = f2.w;
        inp[12] = f3.x; inp[13] = f3.y; inp[14] = f3.z; inp[15] = f3.w;
    }
    float dx = dirs[(size_t)i * 3 + 0];
    float dy = dirs[(size_t)i * 3 + 1];
    float dz = dirs[(size_t)i * 3 + 2];
    float nx = normals[(size_t)i * 3 + 0];
    float ny = normals[(size_t)i * 3 + 1];
    float nz = normals[(size_t)i * 3 + 2];

    // ---- reflect ----
    float dn = dx * nx + dy * ny + dz * nz;
    float x = dx - 2.0f * dn * nx;
    float y = dy - 2.0f * dn * ny;
    float z = dz - 2.0f * dn * nz;

    // ---- SH degree-4 basis (16 terms) ----
    float xy = x * y, xz = x * z, yz = y * z;
    float x2 = x * x, y2 = y * y, z2 = z * z;
    inp[16] = 0.28209479177387814f;
    inp[17] = -0.48860251190291987f * y;
    inp[18] =  0.48860251190291987f * z;
    inp[19] = -0.48860251190291987f * x;
    inp[20] =  1.0925484305920792f * xy;
    inp[21] = -1.0925484305920792f * yz;
    inp[22] =  0.94617469575755997f * z2 - 0.31539156525251999f;
    inp[23] = -1.0925484305920792f * xz;
    inp[24] =  0.54627421529603959f * (x2 - y2);
    inp[25] =  0.59004358992664352f * y * (-3.0f * x2 + y2);
    inp[26] =  2.8906114426405538f * xy * z;
    inp[27] =  0.45704579946446572f * y * (1.0f - 5.0f * z2);
    inp[28] =  0.3731763325901154f * z * (5.0f * z2 - 3.0f);
    inp[29] =  0.45704579946446572f * x * (1.0f - 5.0f * z2);
    inp[30] =  1.4453057213202769f * z * (x2 - y2);
    inp[31] =  0.59004358992664352f * x * (-x2 + 3.0f * y2);
    inp[32] = nx;
    inp[33] = ny;
    inp[34] = nz;

    // ---- layer 1: [35] x [35,64] + relu ----
    float h1[HID];
    #pragma unroll
    for (int j = 0; j < HID; ++j) h1[j] = 0.0f;
    #pragma unroll
    for (int k = 0; k < IN_DIM; ++k) {
        float v = inp[k];
        #pragma unroll
        for (int j = 0; j < HID; ++j)
            h1[j] = fmaf(v, W1[k * HID + j], h1[j]);
    }
    #pragma unroll
    for (int j = 0; j < HID; ++j) h1[j] = fmaxf(h1[j], 0.0f);

    // ---- layer 2: [64] x [64,64] + relu ----
    float h2[HID];
    #pragma unroll
    for (int j = 0; j < HID; ++j) h2[j] = 0.0f;
    #pragma unroll
    for (int k = 0; k < HID; ++k) {
        float v = h1[k];
        #pragma unroll
        for (int j = 0; j < HID; ++j)
            h2[j] = fmaf(v, W2[k * HID + j], h2[j]);
    }
    #pragma unroll
    for (int j = 0; j < HID; ++j) h2[j] = fmaxf(h2[j], 0.0f);

    // ---- layer 3: [64] x [64,3] + sigmoid ----
    float o0 = 0.0f, o1 = 0.0f, o2 = 0.0f;
    #pragma unroll
    for (int k = 0; k < HID; ++k) {
        float v = h2[k];
        o0 = fmaf(v, W3[k * 3 + 0], o0);
        o1 = fmaf(v, W3[k * 3 + 1], o1);
        o2 = fmaf(v, W3[k * 3 + 2], o2);
    }
    o0 = 1.0f / (1.0f + __expf(-o0));
    o1 = 1.0f / (1.0f + __expf(-o1));
    o2 = 1.0f / (1.0f + __expf(-o2));

    out[(size_t)i * 3 + 0] = o0;
    out[(size_t)i * 3 + 1] = o1;
    out[(size_t)i * 3 + 2] = o2;
}

extern "C" void kernel_launch(void* const* d_in, const int* in_sizes, int n_in,
                              void* d_out, int out_size, void* d_ws, size_t ws_size,
                              hipStream_t stream) {
    const float* features = (const float*)d_in[0];
    const float* dirs     = (const float*)d_in[1];
    const float* normals  = (const float*)d_in[2];
    const float* W1       = (const float*)d_in[3];
    const float* W2       = (const float*)d_in[4];
    const float* W3       = (const float*)d_in[5];
    float* out = (float*)d_out;

    const int block = 256;
    const int grid = NS / block;  // 2097152 / 256 = 8192
    radiance_fp32_kernel<<<grid, block, 0, stream>>>(
        features, dirs, normals, W1, W2, W3, out);
}

// Round 2
// 326.921 us; speedup vs baseline: 1.5986x; 1.5986x over previous
//
#include <hip/hip_runtime.h>
#include <hip/hip_bf16.h>
#include <math.h>

#define NS 2097152
#define NGROUP (NS / 16)        // 131072 groups of 16 samples
#define NBLOCK 1024
#define NWAVES (NBLOCK * 4)     // 4096 waves

typedef __attribute__((ext_vector_type(8))) short bf16x8;
typedef __attribute__((ext_vector_type(4))) float f32x4;

union FragU { unsigned u[4]; bf16x8 v; };

__device__ __forceinline__ unsigned pkbf16(float lo, float hi) {
    union { __hip_bfloat162 h; unsigned u; } cv;
    cv.h = __halves2bfloat162(__float2bfloat16(lo), __float2bfloat16(hi));
    return cv.u;
}

__device__ __forceinline__ float sigmoidf_(float x) {
    return 1.0f / (1.0f + expf(-x));
}

__global__ __launch_bounds__(256, 2) void radiance_mfma_kernel(
    const float* __restrict__ features,
    const float* __restrict__ dirs,
    const float* __restrict__ normals,
    const float* __restrict__ W1,   // [35][64]
    const float* __restrict__ W2,   // [64][64]
    const float* __restrict__ W3,   // [64][3]
    float* __restrict__ out)        // [N][3]
{
    __shared__ __align__(16) unsigned char lds[4][4096];  // per-wave: h1 @0, h2 @2048

    const int tid  = threadIdx.x;
    const int wid  = tid >> 6;            // wave in block (0..3)
    const int lane = tid & 63;
    const int s    = lane & 15;           // sample slot / B column
    const int hi   = lane >> 4;           // 0..3
    const int wave_id = blockIdx.x * 4 + wid;

    unsigned char* wb  = &lds[wid][0];
    unsigned char* wb2 = wb + 2048;
    const unsigned sw = (unsigned)((s & 7) << 4);

    const f32x4 zero = {0.f, 0.f, 0.f, 0.f};

    // ================= one-time weight A-fragments =================
    // A = W^T: A[m=out_neuron][k=in], lane holds row m = t*16 + s, k = st*32 + hi*8 + j
    bf16x8 a1[4][2], a2[4][2], a3[2];

    #pragma unroll
    for (int t = 0; t < 4; ++t) {
        #pragma unroll
        for (int st = 0; st < 2; ++st) {
            FragU q;
            #pragma unroll
            for (int d = 0; d < 4; ++d) {
                int k0 = st * 32 + hi * 8 + 2 * d;
                int k1 = k0 + 1;
                int m  = t * 16 + s;
                float w0 = (k0 < 35) ? W1[k0 * 64 + m] : 0.f;
                float w1 = (k1 < 35) ? W1[k1 * 64 + m] : 0.f;
                q.u[d] = pkbf16(w0, w1);
            }
            a1[t][st] = q.v;
        }
    }
    #pragma unroll
    for (int t = 0; t < 4; ++t) {
        #pragma unroll
        for (int st = 0; st < 2; ++st) {
            FragU q;
            #pragma unroll
            for (int d = 0; d < 4; ++d) {
                int k0 = st * 32 + hi * 8 + 2 * d;
                int m  = t * 16 + s;
                q.u[d] = pkbf16(W2[k0 * 64 + m], W2[(k0 + 1) * 64 + m]);
            }
            a2[t][st] = q.v;
        }
    }
    #pragma unroll
    for (int st = 0; st < 2; ++st) {
        FragU q;
        #pragma unroll
        for (int d = 0; d < 4; ++d) {
            int k0 = st * 32 + hi * 8 + 2 * d;
            float w0 = (s < 3) ? W3[k0 * 3 + s] : 0.f;
            float w1 = (s < 3) ? W3[(k0 + 1) * 3 + s] : 0.f;
            q.u[d] = pkbf16(w0, w1);
        }
        a3[st] = q.v;
    }

    // ================= grid-stride over sample groups =================
    for (int g = wave_id; g < NGROUP; g += NWAVES) {
        const size_t smp = (size_t)g * 16 + s;

        // ---- build B1 = X^T fragments (k-step 0: feat+SH, k-step 1: normals+pad) ----
        unsigned u0, u1, u2, u3, v0, v1, v2, v3;
        if (hi < 2) {
            const float* fb = features + smp * 16 + (size_t)hi * 8;
            float4 fA = *(const float4*)fb;
            float4 fB = *(const float4*)(fb + 4);
            u0 = pkbf16(fA.x, fA.y); u1 = pkbf16(fA.z, fA.w);
            u2 = pkbf16(fB.x, fB.y); u3 = pkbf16(fB.z, fB.w);
            if (hi == 0) {
                const float* np = normals + smp * 3;
                float nx = np[0], ny = np[1], nz = np[2];
                v0 = pkbf16(nx, ny); v1 = pkbf16(nz, 0.f); v2 = 0; v3 = 0;
            } else {
                v0 = v1 = v2 = v3 = 0;
            }
        } else {
            const float* dp = dirs + smp * 3;
            const float* np = normals + smp * 3;
            float dx = dp[0], dy = dp[1], dz = dp[2];
            float nx = np[0], ny = np[1], nz = np[2];
            float dn = dx * nx + dy * ny + dz * nz;
            float m2 = -2.0f * dn;
            float x = fmaf(m2, nx, dx);
            float y = fmaf(m2, ny, dy);
            float z = fmaf(m2, nz, dz);
            float xy = x * y, xz = x * z, yz = y * z;
            float x2 = x * x, y2 = y * y, z2 = z * z;
            float sh0 = 0.28209479177387814f;
            float sh1 = -0.48860251190291987f * y;
            float sh2 =  0.48860251190291987f * z;
            float sh3 = -0.48860251190291987f * x;
            float sh4 =  1.0925484305920792f * xy;
            float sh5 = -1.0925484305920792f * yz;
            float sh6 = fmaf(0.94617469575755997f, z2, -0.31539156525251999f);
            float sh7 = -1.0925484305920792f * xz;
            float sh8  = 0.54627421529603959f * (x2 - y2);
            float sh9  = 0.59004358992664352f * y * fmaf(-3.0f, x2, y2);
            float sh10 = 2.8906114426405538f * xy * z;
            float sh11 = 0.45704579946446572f * y * fmaf(-5.0f, z2, 1.0f);
            float sh12 = 0.3731763325901154f * z * fmaf(5.0f, z2, -3.0f);
            float sh13 = 0.45704579946446572f * x * fmaf(-5.0f, z2, 1.0f);
            float sh14 = 1.4453057213202769f * z * (x2 - y2);
            float sh15 = 0.59004358992664352f * x * fmaf(-1.0f, x2, 3.0f * y2);
            unsigned e0 = pkbf16(sh0, sh1),  e1 = pkbf16(sh2, sh3);
            unsigned e2 = pkbf16(sh4, sh5),  e3 = pkbf16(sh6, sh7);
            unsigned f0 = pkbf16(sh8, sh9),  f1 = pkbf16(sh10, sh11);
            unsigned f2 = pkbf16(sh12, sh13), f3 = pkbf16(sh14, sh15);
            bool odd = (hi & 1);
            u0 = odd ? f0 : e0; u1 = odd ? f1 : e1;
            u2 = odd ? f2 : e2; u3 = odd ? f3 : e3;
            v0 = v1 = v2 = v3 = 0;
        }
        bf16x8 B0, B1v;
        { FragU q; q.u[0] = u0; q.u[1] = u1; q.u[2] = u2; q.u[3] = u3; B0 = q.v; }
        { FragU q; q.u[0] = v0; q.u[1] = v1; q.u[2] = v2; q.u[3] = v3; B1v = q.v; }

        // ---- layer 1: H1^T = W1^T @ X^T ----
        f32x4 acc1[4];
        #pragma unroll
        for (int t = 0; t < 4; ++t)
            acc1[t] = __builtin_amdgcn_mfma_f32_16x16x32_bf16(a1[t][0], B0, zero, 0, 0, 0);
        #pragma unroll
        for (int t = 0; t < 4; ++t)
            acc1[t] = __builtin_amdgcn_mfma_f32_16x16x32_bf16(a1[t][1], B1v, acc1[t], 0, 0, 0);

        // ---- relu + pack -> LDS (layout: byte = s*128 + n*2, XOR-swizzled) ----
        #pragma unroll
        for (int t = 0; t < 4; ++t) {
            float h0 = fmaxf(acc1[t][0], 0.f), h1_ = fmaxf(acc1[t][1], 0.f);
            float h2_ = fmaxf(acc1[t][2], 0.f), h3_ = fmaxf(acc1[t][3], 0.f);
            unsigned base = (unsigned)(s * 128 + (t * 16 + hi * 4) * 2);
            *(unsigned*)(wb + (base ^ sw))       = pkbf16(h0, h1_);
            *(unsigned*)(wb + ((base + 4) ^ sw)) = pkbf16(h2_, h3_);
        }

        // ---- read B2 = H1^T fragments ----
        bf16x8 hB[2];
        #pragma unroll
        for (int st = 0; st < 2; ++st)
            hB[st] = *(const bf16x8*)(wb + (((unsigned)(s * 128 + st * 64 + hi * 16)) ^ sw));

        // ---- layer 2 ----
        f32x4 acc2[4];
        #pragma unroll
        for (int t = 0; t < 4; ++t)
            acc2[t] = __builtin_amdgcn_mfma_f32_16x16x32_bf16(a2[t][0], hB[0], zero, 0, 0, 0);
        #pragma unroll
        for (int t = 0; t < 4; ++t)
            acc2[t] = __builtin_amdgcn_mfma_f32_16x16x32_bf16(a2[t][1], hB[1], acc2[t], 0, 0, 0);

        // ---- relu + pack -> LDS buffer 2 ----
        #pragma unroll
        for (int t = 0; t < 4; ++t) {
            float h0 = fmaxf(acc2[t][0], 0.f), h1_ = fmaxf(acc2[t][1], 0.f);
            float h2_ = fmaxf(acc2[t][2], 0.f), h3_ = fmaxf(acc2[t][3], 0.f);
            unsigned base = (unsigned)(s * 128 + (t * 16 + hi * 4) * 2);
            *(unsigned*)(wb2 + (base ^ sw))       = pkbf16(h0, h1_);
            *(unsigned*)(wb2 + ((base + 4) ^ sw)) = pkbf16(h2_, h3_);
        }

        // ---- layer 3: D3 = W3^T @ H2^T (rows 0..2 useful) ----
        bf16x8 hC[2];
        #pragma unroll
        for (int st = 0; st < 2; ++st)
            hC[st] = *(const bf16x8*)(wb2 + (((unsigned)(s * 128 + st * 64 + hi * 16)) ^ sw));

        f32x4 acc3 = __builtin_amdgcn_mfma_f32_16x16x32_bf16(a3[0], hC[0], zero, 0, 0, 0);
        acc3 = __builtin_amdgcn_mfma_f32_16x16x32_bf16(a3[1], hC[1], acc3, 0, 0, 0);

        // ---- sigmoid + store (lanes hi==0 hold channels 0..2 for sample s) ----
        float o0 = sigmoidf_(acc3[0]);
        float o1 = sigmoidf_(acc3[1]);
        float o2 = sigmoidf_(acc3[2]);
        if (hi == 0) {
            float* ob = out + ((size_t)g * 16 + s) * 3;
            ob[0] = o0; ob[1] = o1; ob[2] = o2;
        }
    }
}

extern "C" void kernel_launch(void* const* d_in, const int* in_sizes, int n_in,
                              void* d_out, int out_size, void* d_ws, size_t ws_size,
                              hipStream_t stream) {
    const float* features = (const float*)d_in[0];
    const float* dirs     = (const float*)d_in[1];
    const float* normals  = (const float*)d_in[2];
    const float* W1       = (const float*)d_in[3];
    const float* W2       = (const float*)d_in[4];
    const float* W3       = (const float*)d_in[5];
    float* out = (float*)d_out;

    radiance_mfma_kernel<<<NBLOCK, 256, 0, stream>>>(
        features, dirs, normals, W1, W2, W3, out);
}

// Round 3
// 314.300 us; speedup vs baseline: 1.6628x; 1.0402x over previous
//
#include <hip/hip_runtime.h>
#include <hip/hip_bf16.h>
#include <math.h>

#define NS 2097152
#define NGROUP (NS / 16)        // 131072 groups of 16 samples
#define NBLOCK 1024
#define NWAVES (NBLOCK * 4)     // 4096 waves
#define ITERS (NGROUP / NWAVES) // 32, exact

typedef __attribute__((ext_vector_type(8))) short bf16x8;
typedef __attribute__((ext_vector_type(4))) float f32x4;

union FragU { unsigned u[4]; bf16x8 v; };

__device__ __forceinline__ unsigned pkbf16(float lo, float hi) {
    union { __hip_bfloat162 h; unsigned u; } cv;
    cv.h = __halves2bfloat162(__float2bfloat16(lo), __float2bfloat16(hi));
    return cv.u;
}

__global__ __launch_bounds__(256, 4) void radiance_mfma2_kernel(
    const float* __restrict__ features,
    const float* __restrict__ dirs,
    const float* __restrict__ normals,
    const float* __restrict__ W1,   // [35][64]
    const float* __restrict__ W2,   // [64][64]
    const float* __restrict__ W3,   // [64][3]
    float* __restrict__ out)        // [N][3]
{
    __shared__ __align__(16) unsigned char lds[4][4096];  // per-wave: h1 @0, h2 @2048

    const int tid  = threadIdx.x;
    const int wid  = tid >> 6;
    const int lane = tid & 63;
    const int s    = lane & 15;           // sample slot / column
    const int hi   = lane >> 4;           // 0..3
    const int wave_id = blockIdx.x * 4 + wid;

    unsigned char* wb  = &lds[wid][0];
    unsigned char* wb2 = wb + 2048;
    const unsigned sw = (unsigned)((s & 7) << 4);

    const f32x4 zero = {0.f, 0.f, 0.f, 0.f};

    // ---- hoisted, pre-swizzled LDS byte offsets ----
    unsigned wof[4], rof[2];
    #pragma unroll
    for (int t = 0; t < 4; ++t)
        wof[t] = ((unsigned)(s * 128 + t * 32 + hi * 8)) ^ sw;
    #pragma unroll
    for (int st = 0; st < 2; ++st)
        rof[st] = ((unsigned)(s * 128 + st * 64 + hi * 16)) ^ sw;

    // ================= one-time weight A-fragments =================
    // A = W^T: lane holds row m = t*16 + s, k = st*32 + hi*8 + j
    bf16x8 a1[4][2], a2[4][2], a3[2];

    #pragma unroll
    for (int t = 0; t < 4; ++t) {
        #pragma unroll
        for (int st = 0; st < 2; ++st) {
            FragU q;
            #pragma unroll
            for (int d = 0; d < 4; ++d) {
                int k0 = st * 32 + hi * 8 + 2 * d;
                int k1 = k0 + 1;
                int m  = t * 16 + s;
                float w0 = (k0 < 35) ? W1[k0 * 64 + m] : 0.f;
                float w1 = (k1 < 35) ? W1[k1 * 64 + m] : 0.f;
                q.u[d] = pkbf16(w0, w1);
            }
            a1[t][st] = q.v;
        }
    }
    #pragma unroll
    for (int t = 0; t < 4; ++t) {
        #pragma unroll
        for (int st = 0; st < 2; ++st) {
            FragU q;
            #pragma unroll
            for (int d = 0; d < 4; ++d) {
                int k0 = st * 32 + hi * 8 + 2 * d;
                int m  = t * 16 + s;
                q.u[d] = pkbf16(W2[k0 * 64 + m], W2[(k0 + 1) * 64 + m]);
            }
            a2[t][st] = q.v;
        }
    }
    #pragma unroll
    for (int st = 0; st < 2; ++st) {
        FragU q;
        #pragma unroll
        for (int d = 0; d < 4; ++d) {
            int k0 = st * 32 + hi * 8 + 2 * d;
            float w0 = (s < 3) ? W3[k0 * 3 + s] : 0.f;
            float w1 = (s < 3) ? W3[(k0 + 1) * 3 + s] : 0.f;
            q.u[d] = pkbf16(w0, w1);
        }
        a3[st] = q.v;
    }

    // ================= preload first group's inputs =================
    float4 cfA, cfB;
    float cdx, cdy, cdz, cnx, cny, cnz;
    {
        unsigned smp = (unsigned)wave_id * 16u + (unsigned)s;
        if (hi < 2) {
            const float* fb = features + (size_t)smp * 16 + hi * 8;
            cfA = *(const float4*)fb;
            cfB = *(const float4*)(fb + 4);
            if (hi == 0) {
                const float* np = normals + (size_t)smp * 3;
                cnx = np[0]; cny = np[1]; cnz = np[2];
            }
        } else {
            const float* dp = dirs + (size_t)smp * 3;
            const float* np = normals + (size_t)smp * 3;
            cdx = dp[0]; cdy = dp[1]; cdz = dp[2];
            cnx = np[0]; cny = np[1]; cnz = np[2];
        }
    }

    // ================= main loop: consume current, prefetch next =================
    unsigned g = (unsigned)wave_id;
    #pragma unroll 1
    for (int it = 0; it < ITERS; ++it) {
        const unsigned gn   = (it == ITERS - 1) ? g : g + (unsigned)NWAVES;
        const unsigned smpn = gn * 16u + (unsigned)s;

        // ---- build B fragments from current regs, then issue next loads ----
        unsigned u0, u1, u2, u3, v0, v1;
        if (hi < 2) {
            u0 = pkbf16(cfA.x, cfA.y); u1 = pkbf16(cfA.z, cfA.w);
            u2 = pkbf16(cfB.x, cfB.y); u3 = pkbf16(cfB.z, cfB.w);
            if (hi == 0) { v0 = pkbf16(cnx, cny); v1 = pkbf16(cnz, 0.f); }
            else         { v0 = 0; v1 = 0; }
            // prefetch next group's features (+ normals for hi==0)
            const float* fb = features + (size_t)smpn * 16 + hi * 8;
            cfA = *(const float4*)fb;
            cfB = *(const float4*)(fb + 4);
            if (hi == 0) {
                const float* np = normals + (size_t)smpn * 3;
                cnx = np[0]; cny = np[1]; cnz = np[2];
            }
        } else {
            float dn = cdx * cnx + cdy * cny + cdz * cnz;
            float m2 = -2.0f * dn;
            float x = fmaf(m2, cnx, cdx);
            float y = fmaf(m2, cny, cdy);
            float z = fmaf(m2, cnz, cdz);
            float xy = x * y, xz = x * z, yz = y * z;
            float x2 = x * x, y2 = y * y, z2 = z * z;
            float sh0 = 0.28209479177387814f;
            float sh1 = -0.48860251190291987f * y;
            float sh2 =  0.48860251190291987f * z;
            float sh3 = -0.48860251190291987f * x;
            float sh4 =  1.0925484305920792f * xy;
            float sh5 = -1.0925484305920792f * yz;
            float sh6 = fmaf(0.94617469575755997f, z2, -0.31539156525251999f);
            float sh7 = -1.0925484305920792f * xz;
            float sh8  = 0.54627421529603959f * (x2 - y2);
            float sh9  = 0.59004358992664352f * y * fmaf(-3.0f, x2, y2);
            float sh10 = 2.8906114426405538f * xy * z;
            float sh11 = 0.45704579946446572f * y * fmaf(-5.0f, z2, 1.0f);
            float sh12 = 0.3731763325901154f * z * fmaf(5.0f, z2, -3.0f);
            float sh13 = 0.45704579946446572f * x * fmaf(-5.0f, z2, 1.0f);
            float sh14 = 1.4453057213202769f * z * (x2 - y2);
            float sh15 = 0.59004358992664352f * x * fmaf(-1.0f, x2, 3.0f * y2);
            unsigned e0 = pkbf16(sh0, sh1),  e1 = pkbf16(sh2, sh3);
            unsigned e2 = pkbf16(sh4, sh5),  e3 = pkbf16(sh6, sh7);
            unsigned f0 = pkbf16(sh8, sh9),  f1 = pkbf16(sh10, sh11);
            unsigned f2 = pkbf16(sh12, sh13), f3 = pkbf16(sh14, sh15);
            bool odd = (hi & 1);
            u0 = odd ? f0 : e0; u1 = odd ? f1 : e1;
            u2 = odd ? f2 : e2; u3 = odd ? f3 : e3;
            v0 = 0; v1 = 0;
            // prefetch next group's dirs + normals
            const float* dp = dirs + (size_t)smpn * 3;
            const float* np = normals + (size_t)smpn * 3;
            cdx = dp[0]; cdy = dp[1]; cdz = dp[2];
            cnx = np[0]; cny = np[1]; cnz = np[2];
        }
        bf16x8 B0, B1v;
        { FragU q; q.u[0] = u0; q.u[1] = u1; q.u[2] = u2; q.u[3] = u3; B0 = q.v; }
        { FragU q; q.u[0] = v0; q.u[1] = v1; q.u[2] = 0;  q.u[3] = 0;  B1v = q.v; }

        // ---- layer 1 ----
        f32x4 acc1[4];
        #pragma unroll
        for (int t = 0; t < 4; ++t)
            acc1[t] = __builtin_amdgcn_mfma_f32_16x16x32_bf16(a1[t][0], B0, zero, 0, 0, 0);
        #pragma unroll
        for (int t = 0; t < 4; ++t)
            acc1[t] = __builtin_amdgcn_mfma_f32_16x16x32_bf16(a1[t][1], B1v, acc1[t], 0, 0, 0);

        // ---- relu + pack -> LDS (b64 writes) ----
        #pragma unroll
        for (int t = 0; t < 4; ++t) {
            uint2 w;
            w.x = pkbf16(fmaxf(acc1[t][0], 0.f), fmaxf(acc1[t][1], 0.f));
            w.y = pkbf16(fmaxf(acc1[t][2], 0.f), fmaxf(acc1[t][3], 0.f));
            *(uint2*)(wb + wof[t]) = w;
        }
        bf16x8 hB0 = *(const bf16x8*)(wb + rof[0]);
        bf16x8 hB1 = *(const bf16x8*)(wb + rof[1]);

        // ---- layer 2 ----
        f32x4 acc2[4];
        #pragma unroll
        for (int t = 0; t < 4; ++t)
            acc2[t] = __builtin_amdgcn_mfma_f32_16x16x32_bf16(a2[t][0], hB0, zero, 0, 0, 0);
        #pragma unroll
        for (int t = 0; t < 4; ++t)
            acc2[t] = __builtin_amdgcn_mfma_f32_16x16x32_bf16(a2[t][1], hB1, acc2[t], 0, 0, 0);

        // ---- relu + pack -> LDS buffer 2 ----
        #pragma unroll
        for (int t = 0; t < 4; ++t) {
            uint2 w;
            w.x = pkbf16(fmaxf(acc2[t][0], 0.f), fmaxf(acc2[t][1], 0.f));
            w.y = pkbf16(fmaxf(acc2[t][2], 0.f), fmaxf(acc2[t][3], 0.f));
            *(uint2*)(wb2 + wof[t]) = w;
        }
        bf16x8 hC0 = *(const bf16x8*)(wb2 + rof[0]);
        bf16x8 hC1 = *(const bf16x8*)(wb2 + rof[1]);

        // ---- layer 3 ----
        f32x4 acc3 = __builtin_amdgcn_mfma_f32_16x16x32_bf16(a3[0], hC0, zero, 0, 0, 0);
        acc3 = __builtin_amdgcn_mfma_f32_16x16x32_bf16(a3[1], hC1, acc3, 0, 0, 0);

        // ---- sigmoid + store ----
        float o0 = __fdividef(1.0f, 1.0f + __expf(-acc3[0]));
        float o1 = __fdividef(1.0f, 1.0f + __expf(-acc3[1]));
        float o2 = __fdividef(1.0f, 1.0f + __expf(-acc3[2]));
        if (hi == 0) {
            float* ob = out + (size_t)(g * 16u + (unsigned)s) * 3;
            ob[0] = o0; ob[1] = o1; ob[2] = o2;
        }
        g = gn;
    }
}

extern "C" void kernel_launch(void* const* d_in, const int* in_sizes, int n_in,
                              void* d_out, int out_size, void* d_ws, size_t ws_size,
                              hipStream_t stream) {
    const float* features = (const float*)d_in[0];
    const float* dirs     = (const float*)d_in[1];
    const float* normals  = (const float*)d_in[2];
    const float* W1       = (const float*)d_in[3];
    const float* W2       = (const float*)d_in[4];
    const float* W3       = (const float*)d_in[5];
    float* out = (float*)d_out;

    radiance_mfma2_kernel<<<NBLOCK, 256, 0, stream>>>(
        features, dirs, normals, W1, W2, W3, out);
}